// Round 4
// baseline (699.834 us; speedup 1.0000x reference)
//
#include <hip/hip_runtime.h>

// GCN 2-layer on MI355X — Round 4: partition-bucket sort + LDS-accumulator
// aggregation (no global atomics, no per-node CSR, no srcsorted array).
//
// agg[i] = dinv[i] * (sum_{e:dst=i} hs[src_e] + hs[i]),  hs[j] = (x@W)[j]*dinv[j]
//
// Partition p = dst>>9 (512 nodes each, P=391). Pipeline:
//   bucket_count -> col_scan -> total_scan -> bucket_scatter (packed u32 =
//   (localdst<<18)|src) -> dinv (per-partition LDS degree hist) -> node1 ->
//   agg1 (LDS float accumulators + fused ReLU/W2 epilogue -> hs2) ->
//   agg2 (LDS accumulators -> out).
//
// ws (4B words): colTotal[1024] | colStart[512] | cntmat[B*P] | packed[E]
//   | dinv[n] | hs1[8n] | hs2[4n]   (~37 MB)

#define EPB   16384  // edges per block in bucket kernels
#define PART  512    // nodes per partition
#define MAXP  512    // >= P = ceil(n/512) = 391

__global__ __launch_bounds__(512) void bucket_count_kernel(
    const int* __restrict__ dst, int* __restrict__ cntmat, int E, int P) {
    __shared__ int cnt[MAXP];
    int tid = threadIdx.x;
    for (int p = tid; p < P; p += 512) cnt[p] = 0;
    __syncthreads();
    int base = blockIdx.x * EPB;
    for (int k = 0; k < EPB; k += 512) {
        int e = base + k + tid;
        if (e < E) atomicAdd(&cnt[dst[e] >> 9], 1);
    }
    __syncthreads();
    int* row = cntmat + (size_t)blockIdx.x * P;
    for (int p = tid; p < P; p += 512) row[p] = cnt[p];
}

// One block per partition column: exclusive scan of cnt[b][p] over b (in
// place), column total -> colTotal[p]. B <= 512.
__global__ __launch_bounds__(256) void col_scan_kernel(
    int* __restrict__ cntmat, int* __restrict__ colTotal, int B, int P) {
    __shared__ int sdata[256];
    int p = blockIdx.x, tid = threadIdx.x;
    int b0 = 2 * tid, b1 = 2 * tid + 1;
    int v0 = (b0 < B) ? cntmat[(size_t)b0 * P + p] : 0;
    int v1 = (b1 < B) ? cntmat[(size_t)b1 * P + p] : 0;
    int s = v0 + v1;
    int x = s;
    sdata[tid] = x;
    __syncthreads();
    for (int off = 1; off < 256; off <<= 1) {
        int t = (tid >= off) ? sdata[tid - off] : 0;
        __syncthreads();
        x += t;
        sdata[tid] = x;
        __syncthreads();
    }
    int run = x - s;
    if (b0 < B) cntmat[(size_t)b0 * P + p] = run;
    if (b1 < B) cntmat[(size_t)b1 * P + p] = run + v0;
    if (tid == 255) colTotal[p] = x;
}

// Single block: exclusive scan of colTotal[P] -> colStart[P+1].
__global__ __launch_bounds__(256) void total_scan_kernel(
    const int* __restrict__ colTotal, int* __restrict__ colStart,
    int P, int E) {
    __shared__ int sdata[256];
    int tid = threadIdx.x;
    int v[4];
    int s = 0;
    #pragma unroll
    for (int k = 0; k < 4; k++) {
        int i = tid * 4 + k;
        v[k] = (i < P) ? colTotal[i] : 0;
        s += v[k];
    }
    int x = s;
    sdata[tid] = x;
    __syncthreads();
    for (int off = 1; off < 256; off <<= 1) {
        int t = (tid >= off) ? sdata[tid - off] : 0;
        __syncthreads();
        x += t;
        sdata[tid] = x;
        __syncthreads();
    }
    int run = x - s;
    #pragma unroll
    for (int k = 0; k < 4; k++) {
        int i = tid * 4 + k;
        if (i < P) colStart[i] = run;
        run += v[k];
    }
    if (tid == 0) colStart[P] = E;
}

// Scatter edges into partition buckets via LDS cursors.
// packed = (localdst<<18)|src  (src < 2^18, localdst < 2^9).
__global__ __launch_bounds__(512) void bucket_scatter_kernel(
    const int* __restrict__ src, const int* __restrict__ dst,
    const int* __restrict__ cntmat, const int* __restrict__ colStart,
    unsigned* __restrict__ packed, int E, int P) {
    __shared__ int cur[MAXP];
    int tid = threadIdx.x;
    const int* row = cntmat + (size_t)blockIdx.x * P;
    for (int p = tid; p < P; p += 512) cur[p] = colStart[p] + row[p];
    __syncthreads();
    int base = blockIdx.x * EPB;
    for (int k = 0; k < EPB; k += 512) {
        int e = base + k + tid;
        if (e < E) {
            int d = dst[e];
            int pos = atomicAdd(&cur[d >> 9], 1);
            packed[pos] = ((unsigned)(d & 511) << 18) | (unsigned)src[e];
        }
    }
}

// One block per partition: LDS degree histogram -> dinv.
__global__ __launch_bounds__(512) void dinv_kernel(
    const unsigned* __restrict__ packed, const int* __restrict__ colStart,
    float* __restrict__ dinv, int n) {
    __shared__ int hist[PART];
    int p = blockIdx.x, tid = threadIdx.x;
    hist[tid] = 0;
    __syncthreads();
    int s0 = colStart[p], s1 = colStart[p + 1];
    for (int i = s0 + tid; i < s1; i += 512)
        atomicAdd(&hist[packed[i] >> 18], 1);
    __syncthreads();
    int node = (p << 9) + tid;
    if (node < n) dinv[node] = rsqrtf((float)hist[tid] + 1.0f);  // +1 self-loop
}

__global__ __launch_bounds__(256) void node1_kernel(
    const float* __restrict__ x, const float* __restrict__ dinv,
    const float* __restrict__ W1, float* __restrict__ hs1, int n) {
    int i = blockIdx.x * blockDim.x + threadIdx.x;
    if (i >= n) return;
    float d = dinv[i];
    float x0 = x[2 * i], x1 = x[2 * i + 1];
    float4 o0, o1;
    o0.x = (x0 * W1[0] + x1 * W1[8])  * d;
    o0.y = (x0 * W1[1] + x1 * W1[9])  * d;
    o0.z = (x0 * W1[2] + x1 * W1[10]) * d;
    o0.w = (x0 * W1[3] + x1 * W1[11]) * d;
    o1.x = (x0 * W1[4] + x1 * W1[12]) * d;
    o1.y = (x0 * W1[5] + x1 * W1[13]) * d;
    o1.z = (x0 * W1[6] + x1 * W1[14]) * d;
    o1.w = (x0 * W1[7] + x1 * W1[15]) * d;
    float4* outp = (float4*)(hs1 + 8 * i);
    outp[0] = o0;
    outp[1] = o1;
}

// One block per partition: gather hs1[src] for the partition's edges into
// SoA LDS accumulators (bank = localdst%32), then fused node2 epilogue
// (ReLU + W2 + dinv scale) -> hs2.
__global__ __launch_bounds__(512) void agg1_kernel(
    const unsigned* __restrict__ packed, const int* __restrict__ colStart,
    const float* __restrict__ hs1, const float* __restrict__ dinv,
    const float* __restrict__ b1, const float* __restrict__ W2,
    float* __restrict__ hs2, int n) {
    __shared__ float acc[8][PART];
    int p = blockIdx.x, tid = threadIdx.x;
    #pragma unroll
    for (int f = 0; f < 8; f++) acc[f][tid] = 0.0f;
    __syncthreads();
    int s0 = colStart[p], s1 = colStart[p + 1];
    for (int i = s0 + tid; i < s1; i += 512) {
        unsigned w = packed[i];
        int s = (int)(w & 0x3FFFFu);
        int ld = (int)(w >> 18);
        const float4* hp = (const float4*)(hs1 + 8 * s);
        float4 a = hp[0], b = hp[1];
        atomicAdd(&acc[0][ld], a.x);
        atomicAdd(&acc[1][ld], a.y);
        atomicAdd(&acc[2][ld], a.z);
        atomicAdd(&acc[3][ld], a.w);
        atomicAdd(&acc[4][ld], b.x);
        atomicAdd(&acc[5][ld], b.y);
        atomicAdd(&acc[6][ld], b.z);
        atomicAdd(&acc[7][ld], b.w);
    }
    __syncthreads();
    int node = (p << 9) + tid;
    if (node >= n) return;
    float d = dinv[node];
    float h[8];
    #pragma unroll
    for (int f = 0; f < 8; f++)
        h[f] = fmaxf(d * (acc[f][tid] + hs1[8 * node + f]) + b1[f], 0.0f);
    float oc[4];
    #pragma unroll
    for (int c = 0; c < 4; c++) {
        float a = 0.0f;
        #pragma unroll
        for (int f = 0; f < 8; f++) a += h[f] * W2[4 * f + c];
        oc[c] = a * d;
    }
    float4 o;
    o.x = oc[0]; o.y = oc[1]; o.z = oc[2]; o.w = oc[3];
    *(float4*)(hs2 + 4 * node) = o;
}

// One block per partition: gather hs2[src], accumulate, write final output.
__global__ __launch_bounds__(512) void agg2_kernel(
    const unsigned* __restrict__ packed, const int* __restrict__ colStart,
    const float* __restrict__ hs2, const float* __restrict__ dinv,
    const float* __restrict__ b2, float* __restrict__ out, int n) {
    __shared__ float acc[4][PART];
    int p = blockIdx.x, tid = threadIdx.x;
    #pragma unroll
    for (int f = 0; f < 4; f++) acc[f][tid] = 0.0f;
    __syncthreads();
    int s0 = colStart[p], s1 = colStart[p + 1];
    for (int i = s0 + tid; i < s1; i += 512) {
        unsigned w = packed[i];
        int s = (int)(w & 0x3FFFFu);
        int ld = (int)(w >> 18);
        float4 a = *(const float4*)(hs2 + 4 * s);
        atomicAdd(&acc[0][ld], a.x);
        atomicAdd(&acc[1][ld], a.y);
        atomicAdd(&acc[2][ld], a.z);
        atomicAdd(&acc[3][ld], a.w);
    }
    __syncthreads();
    int node = (p << 9) + tid;
    if (node >= n) return;
    float d = dinv[node];
    float4 o;
    o.x = d * (acc[0][tid] + hs2[4 * node + 0]) + b2[0];
    o.y = d * (acc[1][tid] + hs2[4 * node + 1]) + b2[1];
    o.z = d * (acc[2][tid] + hs2[4 * node + 2]) + b2[2];
    o.w = d * (acc[3][tid] + hs2[4 * node + 3]) + b2[3];
    *(float4*)(out + 4 * node) = o;
}

extern "C" void kernel_launch(void* const* d_in, const int* in_sizes, int n_in,
                              void* d_out, int out_size, void* d_ws, size_t ws_size,
                              hipStream_t stream) {
    const float* x   = (const float*)d_in[0];
    const int*   ei  = (const int*)d_in[1];
    const float* W1  = (const float*)d_in[2];
    const float* b1  = (const float*)d_in[3];
    const float* W2  = (const float*)d_in[4];
    const float* b2  = (const float*)d_in[5];
    float* out = (float*)d_out;

    const int n = in_sizes[0] / 2;  // x is [N,2]
    const int E = in_sizes[1] / 2;  // edge_index is [2,E]
    const int* src = ei;
    const int* dst = ei + E;

    const int P = (n + PART - 1) / PART;   // 391 partitions of 512 nodes
    const int B = (E + EPB - 1) / EPB;     // 391 edge blocks

    int* ws = (int*)d_ws;
    int* colTotal = ws;                                    // pad 1024
    int* colStart = ws + 1024;                             // P+1 (pad 512)
    int* cntmat   = ws + 1536;                             // B*P
    size_t cm = ((size_t)B * P + 3) & ~(size_t)3;
    unsigned* packed = (unsigned*)(cntmat + cm);           // E (live to end)
    float* dinv = (float*)(packed + E);                    // n
    float* hs1  = dinv + n;                                // 8n
    float* hs2  = hs1 + 8 * (size_t)n;                     // 4n

    const int gN = (n + 255) / 256;

    bucket_count_kernel  <<<B, 512, 0, stream>>>(dst, cntmat, E, P);
    col_scan_kernel      <<<P, 256, 0, stream>>>(cntmat, colTotal, B, P);
    total_scan_kernel    <<<1, 256, 0, stream>>>(colTotal, colStart, P, E);
    bucket_scatter_kernel<<<B, 512, 0, stream>>>(src, dst, cntmat, colStart, packed, E, P);
    dinv_kernel          <<<P, 512, 0, stream>>>(packed, colStart, dinv, n);
    node1_kernel         <<<gN, 256, 0, stream>>>(x, dinv, W1, hs1, n);
    agg1_kernel          <<<P, 512, 0, stream>>>(packed, colStart, hs1, dinv, b1, W2, hs2, n);
    agg2_kernel          <<<P, 512, 0, stream>>>(packed, colStart, hs2, dinv, b2, out, n);
}

// Round 5
// 450.466 us; speedup vs baseline: 1.5536x; 1.5536x over previous
//
#include <hip/hip_runtime.h>

// GCN 2-layer on MI355X — Round 5: rank-2 gather + L2-resident working sets.
//
// g[j] = x[j]*dinv[j] (2 floats).  layer1: agg[i]=dinv[i]*(sum g[src]+g[i])@W1+b1
// h = relu(agg); hs2 = (h@W2)*dinv;  out[i] = dinv[i]*(sum hs2[src]+hs2[i])+b2
//
// Partition p = dst>>11 (2048 nodes, P=98). packed = (localdst<<18)|src (29b).
// Aggregation: P*C chunk-blocks with private LDS accumulators -> partial dump
// (coalesced) -> per-node reduce with fused dense epilogue.
//
// ws (words): colTotal[1024] | colStart[1024] | cntmat[782*98 pad] | packed[E]
//  | dinv[n] | g[2n] | hs2[4n] | partial[6.42M]  (~57 MB)

#define EPB   8192   // edges per bucket block
#define PART  2048   // nodes per partition
#define LPBIT 11
#define SRCB  18     // src bits in packed
#define C1    16     // layer-1 chunks per partition
#define C2    8      // layer-2 chunks per partition

__global__ __launch_bounds__(512) void bucket_count_kernel(
    const int* __restrict__ dst, int* __restrict__ cntmat, int E, int P) {
    __shared__ int cnt[128];
    int tid = threadIdx.x;
    if (tid < 128) cnt[tid] = 0;
    __syncthreads();
    int base = blockIdx.x * EPB;
    #pragma unroll
    for (int k = 0; k < EPB; k += 512) {
        int e = base + k + tid;
        if (e < E) atomicAdd(&cnt[dst[e] >> LPBIT], 1);
    }
    __syncthreads();
    int* row = cntmat + (size_t)blockIdx.x * P;
    if (tid < P) row[tid] = cnt[tid];
}

// One block per partition column: exclusive scan over B block-counts.
__global__ __launch_bounds__(256) void col_scan_kernel(
    int* __restrict__ cntmat, int* __restrict__ colTotal, int B, int P) {
    __shared__ int sdata[256];
    int p = blockIdx.x, tid = threadIdx.x;
    int v[4];
    int s = 0;
    #pragma unroll
    for (int k = 0; k < 4; k++) {
        int b = tid * 4 + k;
        v[k] = (b < B) ? cntmat[(size_t)b * P + p] : 0;
        s += v[k];
    }
    int x = s;
    sdata[tid] = x;
    __syncthreads();
    for (int off = 1; off < 256; off <<= 1) {
        int t = (tid >= off) ? sdata[tid - off] : 0;
        __syncthreads();
        x += t;
        sdata[tid] = x;
        __syncthreads();
    }
    int run = x - s;
    #pragma unroll
    for (int k = 0; k < 4; k++) {
        int b = tid * 4 + k;
        if (b < B) cntmat[(size_t)b * P + p] = run;
        run += v[k];
    }
    if (tid == 255) colTotal[p] = x;
}

// Single block: exclusive scan colTotal[P] -> colStart[P+1].
__global__ __launch_bounds__(256) void total_scan_kernel(
    const int* __restrict__ colTotal, int* __restrict__ colStart,
    int P, int E) {
    __shared__ int sdata[256];
    int tid = threadIdx.x;
    int v[4];
    int s = 0;
    #pragma unroll
    for (int k = 0; k < 4; k++) {
        int i = tid * 4 + k;
        v[k] = (i < P) ? colTotal[i] : 0;
        s += v[k];
    }
    int x = s;
    sdata[tid] = x;
    __syncthreads();
    for (int off = 1; off < 256; off <<= 1) {
        int t = (tid >= off) ? sdata[tid - off] : 0;
        __syncthreads();
        x += t;
        sdata[tid] = x;
        __syncthreads();
    }
    int run = x - s;
    #pragma unroll
    for (int k = 0; k < 4; k++) {
        int i = tid * 4 + k;
        if (i < P) colStart[i] = run;
        run += v[k];
    }
    if (tid == 0) colStart[P] = E;
}

__global__ __launch_bounds__(512) void bucket_scatter_kernel(
    const int* __restrict__ src, const int* __restrict__ dst,
    const int* __restrict__ cntmat, const int* __restrict__ colStart,
    unsigned* __restrict__ packed, int E, int P) {
    __shared__ int cur[128];
    int tid = threadIdx.x;
    if (tid < P) cur[tid] = colStart[tid] + cntmat[(size_t)blockIdx.x * P + tid];
    __syncthreads();
    int base = blockIdx.x * EPB;
    #pragma unroll
    for (int k = 0; k < EPB; k += 512) {
        int e = base + k + tid;
        if (e < E) {
            int d = dst[e];
            int pos = atomicAdd(&cur[d >> LPBIT], 1);
            packed[pos] = ((unsigned)(d & (PART - 1)) << SRCB) | (unsigned)src[e];
        }
    }
}

// One block per partition: per-node degree hist -> dinv and g = x*dinv.
__global__ __launch_bounds__(512) void dinv_g_kernel(
    const unsigned* __restrict__ packed, const int* __restrict__ colStart,
    const float* __restrict__ x, float* __restrict__ dinv,
    float* __restrict__ g, int n) {
    __shared__ int hist[PART];
    int p = blockIdx.x, tid = threadIdx.x;
    for (int i = tid; i < PART; i += 512) hist[i] = 0;
    __syncthreads();
    int s0 = colStart[p], s1 = colStart[p + 1];
    for (int i = s0 + tid; i < s1; i += 512)
        atomicAdd(&hist[packed[i] >> SRCB], 1);
    __syncthreads();
    const float2* xp = (const float2*)x;
    float2* gp = (float2*)g;
    for (int j = tid; j < PART; j += 512) {
        int node = (p << LPBIT) + j;
        if (node < n) {
            float d = rsqrtf((float)hist[j] + 1.0f);  // +1 self-loop
            dinv[node] = d;
            float2 xv = xp[node];
            gp[node] = make_float2(xv.x * d, xv.y * d);
        }
    }
}

// Chunked layer-1 aggregation: block = (p, c); 2-float LDS accumulators.
__global__ __launch_bounds__(256) void agg1_kernel(
    const unsigned* __restrict__ packed, const int* __restrict__ colStart,
    const float* __restrict__ g, float* __restrict__ partial) {
    __shared__ float acc[2 * PART];
    int tid = threadIdx.x;
    int p = blockIdx.x >> 4, c = blockIdx.x & (C1 - 1);
    for (int i = tid; i < 2 * PART; i += 256) acc[i] = 0.0f;
    __syncthreads();
    int s0 = colStart[p], s1 = colStart[p + 1], len = s1 - s0;
    int cs = s0 + (len * c) / C1, ce = s0 + (len * (c + 1)) / C1;
    const float2* gp = (const float2*)g;
    for (int i = cs + tid; i < ce; i += 256) {
        unsigned w = packed[i];
        int s = (int)(w & ((1u << SRCB) - 1));
        int ld = (int)(w >> SRCB);
        float2 gv = gp[s];
        atomicAdd(&acc[ld], gv.x);
        atomicAdd(&acc[PART + ld], gv.y);
    }
    __syncthreads();
    float2* pp = (float2*)partial + (size_t)blockIdx.x * PART;
    for (int i = tid; i < PART; i += 256)
        pp[i] = make_float2(acc[i], acc[PART + i]);
}

// Per-node reduce + fused dense epilogue: W1 + b1 + ReLU + W2 + dinv -> hs2.
__global__ __launch_bounds__(256) void reduce1_kernel(
    const float* __restrict__ partial, const float* __restrict__ g,
    const float* __restrict__ dinv, const float* __restrict__ W1,
    const float* __restrict__ b1, const float* __restrict__ W2,
    float* __restrict__ hs2, int n) {
    int i = blockIdx.x * 256 + threadIdx.x;
    if (i >= n) return;
    int p = i >> LPBIT, ld = i & (PART - 1);
    const float2* pp = (const float2*)partial;
    float s0 = 0.0f, s1 = 0.0f;
    #pragma unroll
    for (int c = 0; c < C1; c++) {
        float2 v = pp[(size_t)(p * C1 + c) * PART + ld];
        s0 += v.x;
        s1 += v.y;
    }
    float2 gv = ((const float2*)g)[i];
    float d = dinv[i];
    s0 = (s0 + gv.x) * d;
    s1 = (s1 + gv.y) * d;
    float h[8];
    #pragma unroll
    for (int f = 0; f < 8; f++)
        h[f] = fmaxf(s0 * W1[f] + s1 * W1[8 + f] + b1[f], 0.0f);
    float oc[4];
    #pragma unroll
    for (int k = 0; k < 4; k++) {
        float a = 0.0f;
        #pragma unroll
        for (int f = 0; f < 8; f++) a += h[f] * W2[4 * f + k];
        oc[k] = a * d;
    }
    float4 o;
    o.x = oc[0]; o.y = oc[1]; o.z = oc[2]; o.w = oc[3];
    *(float4*)(hs2 + 4 * (size_t)i) = o;
}

// Chunked layer-2 aggregation: 4-float LDS accumulators.
__global__ __launch_bounds__(256) void agg2_kernel(
    const unsigned* __restrict__ packed, const int* __restrict__ colStart,
    const float* __restrict__ hs2, float* __restrict__ partial) {
    __shared__ float acc[4 * PART];
    int tid = threadIdx.x;
    int p = blockIdx.x >> 3, c = blockIdx.x & (C2 - 1);
    for (int i = tid; i < 4 * PART; i += 256) acc[i] = 0.0f;
    __syncthreads();
    int s0 = colStart[p], s1 = colStart[p + 1], len = s1 - s0;
    int cs = s0 + (len * c) / C2, ce = s0 + (len * (c + 1)) / C2;
    for (int i = cs + tid; i < ce; i += 256) {
        unsigned w = packed[i];
        int s = (int)(w & ((1u << SRCB) - 1));
        int ld = (int)(w >> SRCB);
        float4 v = *(const float4*)(hs2 + 4 * (size_t)s);
        atomicAdd(&acc[ld], v.x);
        atomicAdd(&acc[PART + ld], v.y);
        atomicAdd(&acc[2 * PART + ld], v.z);
        atomicAdd(&acc[3 * PART + ld], v.w);
    }
    __syncthreads();
    float4* pp = (float4*)partial + (size_t)blockIdx.x * PART;
    for (int i = tid; i < PART; i += 256) {
        float4 v;
        v.x = acc[i];
        v.y = acc[PART + i];
        v.z = acc[2 * PART + i];
        v.w = acc[3 * PART + i];
        pp[i] = v;
    }
}

__global__ __launch_bounds__(256) void reduce2_kernel(
    const float* __restrict__ partial, const float* __restrict__ hs2,
    const float* __restrict__ dinv, const float* __restrict__ b2,
    float* __restrict__ out, int n) {
    int i = blockIdx.x * 256 + threadIdx.x;
    if (i >= n) return;
    int p = i >> LPBIT, ld = i & (PART - 1);
    const float4* pp = (const float4*)partial;
    float4 s = make_float4(0.f, 0.f, 0.f, 0.f);
    #pragma unroll
    for (int c = 0; c < C2; c++) {
        float4 v = pp[(size_t)(p * C2 + c) * PART + ld];
        s.x += v.x; s.y += v.y; s.z += v.z; s.w += v.w;
    }
    float4 h = *(const float4*)(hs2 + 4 * (size_t)i);
    float d = dinv[i];
    float4 o;
    o.x = d * (s.x + h.x) + b2[0];
    o.y = d * (s.y + h.y) + b2[1];
    o.z = d * (s.z + h.z) + b2[2];
    o.w = d * (s.w + h.w) + b2[3];
    *(float4*)(out + 4 * (size_t)i) = o;
}

extern "C" void kernel_launch(void* const* d_in, const int* in_sizes, int n_in,
                              void* d_out, int out_size, void* d_ws, size_t ws_size,
                              hipStream_t stream) {
    const float* x   = (const float*)d_in[0];
    const int*   ei  = (const int*)d_in[1];
    const float* W1  = (const float*)d_in[2];
    const float* b1  = (const float*)d_in[3];
    const float* W2  = (const float*)d_in[4];
    const float* b2  = (const float*)d_in[5];
    float* out = (float*)d_out;

    const int n = in_sizes[0] / 2;  // x is [N,2]
    const int E = in_sizes[1] / 2;  // edge_index is [2,E]
    const int* src = ei;
    const int* dst = ei + E;

    const int P = (n + PART - 1) >> LPBIT;  // 98
    const int B = (E + EPB - 1) / EPB;      // 782

    int* ws = (int*)d_ws;
    int* colTotal = ws;                                    // 1024
    int* colStart = ws + 1024;                             // 1024 (P+1 used)
    int* cntmat   = ws + 2048;                             // B*P
    size_t cm = ((size_t)B * P + 3) & ~(size_t)3;
    unsigned* packed = (unsigned*)(cntmat + cm);           // E
    float* dinv = (float*)(packed + E);                    // n
    float* g    = dinv + n;                                // 2n  (8B aligned)
    float* hs2  = g + 2 * (size_t)n;                       // 4n  (16B aligned)
    float* partial = hs2 + 4 * (size_t)n;                  // P*C1*2*PART words

    bucket_count_kernel  <<<B, 512, 0, stream>>>(dst, cntmat, E, P);
    col_scan_kernel      <<<P, 256, 0, stream>>>(cntmat, colTotal, B, P);
    total_scan_kernel    <<<1, 256, 0, stream>>>(colTotal, colStart, P, E);
    bucket_scatter_kernel<<<B, 512, 0, stream>>>(src, dst, cntmat, colStart, packed, E, P);
    dinv_g_kernel        <<<P, 512, 0, stream>>>(packed, colStart, x, dinv, g, n);
    agg1_kernel          <<<P * C1, 256, 0, stream>>>(packed, colStart, g, partial);
    reduce1_kernel       <<<(n + 255) / 256, 256, 0, stream>>>(partial, g, dinv, W1, b1, W2, hs2, n);
    agg2_kernel          <<<P * C2, 256, 0, stream>>>(packed, colStart, hs2, partial);
    reduce2_kernel       <<<(n + 255) / 256, 256, 0, stream>>>(partial, hs2, dinv, b2, out, n);
}